// Round 14
// baseline (213.349 us; speedup 1.0000x reference)
//
#include <hip/hip_runtime.h>

#define N_PIX    32768
#define DIM      64
#define K_CODES  1024
#define BPIX     128          // pixels per block
#define CHUNK    128          // codes per LDS chunk
#define NCHUNK   8            // full K per block: no splits, no partials

// ws layout: [0,4096) c2[1024] ; [4096, +128KiB) idx[N_PIX]

__global__ __launch_bounds__(256) void c2_kernel(const float* __restrict__ cb,
                                                 float* __restrict__ c2) {
    int k = blockIdx.x * 256 + threadIdx.x;
    if (k >= K_CODES) return;
    const float* row = cb + k * DIM;
    float a0 = 0.f, a1 = 0.f, a2 = 0.f, a3 = 0.f;
#pragma unroll
    for (int d = 0; d < DIM; d += 4) {
        a0 = fmaf(row[d + 0], row[d + 0], a0);
        a1 = fmaf(row[d + 1], row[d + 1], a1);
        a2 = fmaf(row[d + 2], row[d + 2], a2);
        a3 = fmaf(row[d + 3], row[d + 3], a3);
    }
    c2[k] = (a0 + a1) + (a2 + a3);
}

// 256 threads = 4 waves (2 prow x 2 kcol); wave = 8wy x 8wx; thread tile 8x8
// (64 acc = proven allocatable max). Block = 128 pix x FULL K as 8 chunks of
// 128 (x staged once, no split redundancy — r11's lesson). LDS 68K -> TWO
// independent blocks/CU: B's waves cover A's barrier/staging stalls (r13 had
// one 103K block/CU, all-wave lockstep at 8 barriers = ~22us DS idle).
// c-scatter k = wc*64 + g*32 + wx*4: c-b128 hits banks 4wx..4wx+3 = all 32,
// conflict-free (r11-proven). Per-CU DS/FMA totals identical to r13.
__global__ __launch_bounds__(256, 2) void argmin_tile(const float* __restrict__ x,
                                                      const float* __restrict__ cb,
                                                      const float* __restrict__ c2,
                                                      int* __restrict__ idx,
                                                      float* __restrict__ quant) {
    __shared__ alignas(16) float xs[DIM * BPIX];     // 32 KB [d][p]
    __shared__ alignas(16) float cs[DIM * CHUNK];    // 32 KB [d][k]
    __shared__ float  xn[BPIX];                      // 512 B
    __shared__ float2 red[2][BPIX];                  // 1 KB
    __shared__ int    sidx[BPIX];                    // 512 B

    const int t      = threadIdx.x;
    const int blk    = blockIdx.x;                   // 0..255 = pixblk
    const int p_base = blk * BPIX;
    const int bb     = p_base >> 10;
    const int hw0    = p_base & 1023;                // 128-aligned: stays in batch

    const float4* x4  = reinterpret_cast<const float4*>(x);
    const float4* cb4 = reinterpret_cast<const float4*>(cb);

    // ---- stage xs[d][p]: rows contiguous in x -> coalesced float4 (8/thread)
#pragma unroll
    for (int i = 0; i < 8; ++i) {
        int fidx = i * 256 + t;           // 0..2047
        int d = fidx >> 5, p4 = fidx & 31;
        reinterpret_cast<float4*>(xs)[d * 32 + p4] =
            x4[(size_t)bb * 16384 + (size_t)d * 256 + (hw0 >> 2) + p4];
    }

    // ---- prefetch chunk-0 codebook tile into regs (k lane-fast: LDS-write
    // conflict-free; cb is 256KB L2-resident)
    float4 creg[8];
#pragma unroll
    for (int i = 0; i < 8; ++i) {
        int fidx = i * 256 + t;           // 0..2047
        int k = fidx & 127, dq = fidx >> 7;
        creg[i] = cb4[(size_t)k * 16 + dq];
    }
    __syncthreads();                      // xs ready

    // ---- xn: EXACT tree of passing rounds (s[d%4] ascending, (s0+s1)+(s2+s3))
    if (t < BPIX) {
        float s0 = 0.f, s1 = 0.f, s2 = 0.f, s3 = 0.f;
#pragma unroll
        for (int d = 0; d < DIM; d += 4) {
            float v0 = xs[(d + 0) * BPIX + t];
            float v1 = xs[(d + 1) * BPIX + t];
            float v2 = xs[(d + 2) * BPIX + t];
            float v3 = xs[(d + 3) * BPIX + t];
            s0 = fmaf(v0, v0, s0);
            s1 = fmaf(v1, v1, s1);
            s2 = fmaf(v2, v2, s2);
            s3 = fmaf(v3, v3, s3);
        }
        xn[t] = (s0 + s1) + (s2 + s3);
    }

    // ---- wave decomposition: 4 waves = 2 prow x 2 kcol
    const int lane = t & 63, w = t >> 6;
    const int wy = lane >> 3, wx = lane & 7;
    const int wr = w >> 1,    wc = w & 1;
    const int pl0 = wr * 64 + wy * 8;     // 0..120
    const int kc0 = wc * 64 + wx * 4;     // scattered: group g at +g*32

    float bv[8]; int bk[8]; float xnr[8];
#pragma unroll
    for (int i = 0; i < 8; ++i) { bv[i] = 1e30f; bk[i] = 0; }

    for (int ch = 0; ch < NCHUNK; ++ch) {
        // write staged tile to cs[d][k] (k lane-fast b32: 2-way alias, free)
#pragma unroll
        for (int i = 0; i < 8; ++i) {
            int fidx = i * 256 + t;
            int k = fidx & 127, dq = fidx >> 7;
            cs[(4 * dq + 0) * CHUNK + k] = creg[i].x;
            cs[(4 * dq + 1) * CHUNK + k] = creg[i].y;
            cs[(4 * dq + 2) * CHUNK + k] = creg[i].z;
            cs[(4 * dq + 3) * CHUNK + k] = creg[i].w;
        }
        if (ch + 1 < NCHUNK) {            // prefetch next chunk under compute
#pragma unroll
            for (int i = 0; i < 8; ++i) {
                int fidx = i * 256 + t;
                int k = fidx & 127, dq = fidx >> 7;
                creg[i] = cb4[(size_t)((ch + 1) * CHUNK + k) * 16 + dq];
            }
        }
        __syncthreads();                  // cs ready (xn too, on first pass)

        if (ch == 0) {
#pragma unroll
            for (int i = 0; i < 8; ++i) xnr[i] = xn[pl0 + i];
        }

        float acc[8][8];                  // j = g*4 + e
#pragma unroll
        for (int i = 0; i < 8; ++i)
#pragma unroll
            for (int j = 0; j < 8; ++j) acc[i][j] = 0.f;

#pragma unroll 4
        for (int d = 0; d < DIM; ++d) {
            const float* xr = xs + d * BPIX + pl0;
            const float* cr = cs + d * CHUNK + kc0;
            float4 xlo = *reinterpret_cast<const float4*>(xr);
            float4 xhi = *reinterpret_cast<const float4*>(xr + 4);
            float4 cfA = *reinterpret_cast<const float4*>(cr);        // g=0
            float4 cfB = *reinterpret_cast<const float4*>(cr + 32);   // g=1
#define ROW(i, xi) \
            acc[i][0] = fmaf(xi, cfA.x, acc[i][0]); \
            acc[i][1] = fmaf(xi, cfA.y, acc[i][1]); \
            acc[i][2] = fmaf(xi, cfA.z, acc[i][2]); \
            acc[i][3] = fmaf(xi, cfA.w, acc[i][3]); \
            acc[i][4] = fmaf(xi, cfB.x, acc[i][4]); \
            acc[i][5] = fmaf(xi, cfB.y, acc[i][5]); \
            acc[i][6] = fmaf(xi, cfB.z, acc[i][6]); \
            acc[i][7] = fmaf(xi, cfB.w, acc[i][7]);
            ROW(0, xlo.x) ROW(1, xlo.y) ROW(2, xlo.z) ROW(3, xlo.w)
            ROW(4, xhi.x) ROW(5, xhi.y) ROW(6, xhi.z) ROW(7, xhi.w)
#undef ROW
        }

        // chunk epilogue: reference rounding (xn - 2*dot) + c2 (exact r2-r13);
        // k ascending within thread across chunks -> strict < = first-min.
        int kg = ch * CHUNK + kc0;
        float4 c2A = *reinterpret_cast<const float4*>(&c2[kg]);
        float4 c2B = *reinterpret_cast<const float4*>(&c2[kg + 32]);
        float c2a[8] = {c2A.x, c2A.y, c2A.z, c2A.w, c2B.x, c2B.y, c2B.z, c2B.w};
#pragma unroll
        for (int i = 0; i < 8; ++i) {
#pragma unroll
            for (int j = 0; j < 8; ++j) {
                float dist = (xnr[i] - 2.0f * acc[i][j]) + c2a[j];
                int   k    = kg + (j >> 2) * 32 + (j & 3);
                if (dist < bv[i]) { bv[i] = dist; bk[i] = k; }
            }
        }
        __syncthreads();                  // all reads of cs done before overwrite
    }

    // ---- cross-wx shuffle reduce: lex (val,k) == global first-min
#pragma unroll
    for (int i = 0; i < 8; ++i) {
#pragma unroll
        for (int off = 1; off <= 4; off <<= 1) {
            float ov = __shfl_xor(bv[i], off);
            int   ok = __shfl_xor(bk[i], off);
            if (ov < bv[i] || (ov == bv[i] && ok < bk[i])) { bv[i] = ov; bk[i] = ok; }
        }
    }
    if (wx == 0) {
#pragma unroll
        for (int i = 0; i < 8; ++i)
            red[wc][pl0 + i] = make_float2(bv[i], __int_as_float(bk[i]));
    }
    __syncthreads();

    // ---- merge 2 code-halves (lex (val,k) = global first-min), emit idx
    if (t < BPIX) {
        float2 r0 = red[0][t], r1 = red[1][t];
        int k0i = __float_as_int(r0.y), k1i = __float_as_int(r1.y);
        float fv = r0.x; int fk = k0i;
        if (r1.x < fv || (r1.x == fv && k1i < fk)) { fv = r1.x; fk = k1i; }
        sidx[t] = fk;
        idx[p_base + t] = fk;
    }
    __syncthreads();

    // ---- fused quantized write: 256 threads; r = t&127 lane-fast -> each
    // 128-lane run stores consecutive hw (coalesced). 32 dims per thread.
    {
        int r = t & 127, q = t >> 7;      // q = dim half
        int fk = sidx[r];
        const float4* crow = cb4 + (size_t)fk * 16 + q * 8;
        float* qb = quant + (size_t)bb * (DIM * 1024) + (size_t)(q * 32) * 1024
                    + (hw0 + r);
#pragma unroll
        for (int dq = 0; dq < 8; ++dq) {
            float4 cv = crow[dq];
            qb[(size_t)(dq * 4 + 0) << 10] = cv.x;
            qb[(size_t)(dq * 4 + 1) << 10] = cv.y;
            qb[(size_t)(dq * 4 + 2) << 10] = cv.z;
            qb[(size_t)(dq * 4 + 3) << 10] = cv.w;
        }
    }
}

// Streaming one-hot writer: flat float4 index e covers enc[n][j0..j0+3],
// n = e>>8, j0 = (e&255)*4. grid-stride, 2048 blocks.
__global__ __launch_bounds__(256) void enc_write(const int* __restrict__ idx,
                                                 float* __restrict__ enc) {
    const int TOT = (N_PIX / 4) * K_CODES;   // 8388608 float4s
    int tid = blockIdx.x * 256 + threadIdx.x;
    float4* enc4 = reinterpret_cast<float4*>(enc);
    for (int e = tid; e < TOT; e += 2048 * 256) {
        int n  = e >> 8;
        int j0 = (e & 255) << 2;
        int ir = idx[n];                 // row-uniform -> L1/L2 broadcast
        float4 v;
        v.x = (ir == j0 + 0) ? 1.0f : 0.0f;
        v.y = (ir == j0 + 1) ? 1.0f : 0.0f;
        v.z = (ir == j0 + 2) ? 1.0f : 0.0f;
        v.w = (ir == j0 + 3) ? 1.0f : 0.0f;
        enc4[e] = v;
    }
}

extern "C" void kernel_launch(void* const* d_in, const int* in_sizes, int n_in,
                              void* d_out, int out_size, void* d_ws, size_t ws_size,
                              hipStream_t stream) {
    const float* x  = (const float*)d_in[0];
    const float* cb = (const float*)d_in[1];

    float* c2  = (float*)d_ws;
    int*   idx = (int*)((char*)d_ws + 4096);

    float* enc   = (float*)d_out;                           // [32768, 1024]
    float* quant = (float*)d_out + (size_t)N_PIX * K_CODES; // [32, 64, 32, 32]

    c2_kernel<<<K_CODES / 256, 256, 0, stream>>>(cb, c2);
    argmin_tile<<<N_PIX / BPIX, 256, 0, stream>>>(x, cb, c2, idx, quant);
    enc_write<<<2048, 256, 0, stream>>>(idx, enc);
}